// Round 2
// baseline (588.640 us; speedup 1.0000x reference)
//
#include <hip/hip_runtime.h>
#include <hip/hip_bf16.h>
#include <math.h>

// Problem constants
#define NN       16384
#define IN_DIM   64
#define CC       4
#define NMAT     (NN * CC)          // 65536 matrices
#define ROWP     18                 // padded row length in complex elements (16 + 2)
#define BUFW     (16 * ROWP * 2)    // floats per buffer = 576
#define MWORDS   (2 * BUFW + 4)     // floats per matrix LDS region = 1156
#define TOFF     BUFW               // T buffer offset (floats) within region
#define TAYLOR_D 10
#define MPB      8                  // matrices per block (128 threads, 2 waves)

// ---------------------------------------------------------------------------
// Fused: per 16x16 complex matrix (n,c):
//   B   = sum_k dX[n,k] * (Ar + i*Ai)[k,c]         (vectorized row loads)
//   AX  = 0.5*(B - B^H)                            (transpose via LDS, once)
//   s   = max(0, ceil(log2(||AX||_1)))             (induced 1-norm)
//   P   = expm(AX / 2^s)  via Horner Taylor deg 10, then s squarings
// One matrix per 16-lane group; 4x4 complex tile per lane; all LDS traffic
// is same-wave (DS ops are in-order within a wave -> no barriers).
// Output: real part only (float32, N*C*256) unless out_size says interleaved.
// ---------------------------------------------------------------------------
__global__ __launch_bounds__(128)
void fused_expm_kernel(const float* __restrict__ dX, const float* __restrict__ Ar,
                       const float* __restrict__ Ai, float* __restrict__ out,
                       const int real_only)
{
    __shared__ __align__(16) float lds[MPB * MWORDS];

    const int t   = threadIdx.x;
    const int grp = t >> 4;        // matrix within block (0..7)
    const int sub = t & 15;
    const int si  = sub >> 2, sj = sub & 3;
    const int i0  = si * 4,  j0 = sj * 4;

    float* mat = lds + grp * MWORDS;  // A buffer
    float* tb  = mat + TOFF;          // T buffer

    const int m = blockIdx.x * MPB + grp;   // matrix index
    const int n = m >> 2;
    const int c = m & 3;

    // ---- Step 1: B tile (rows i0..i0+3, cols j0..j0+3)
    float2 b[4][4];
#pragma unroll
    for (int r = 0; r < 4; ++r)
#pragma unroll
        for (int jj = 0; jj < 4; ++jj) b[r][jj] = make_float2(0.f, 0.f);

    const float* dxp = dX + n * IN_DIM;
#pragma unroll 2
    for (int k = 0; k < IN_DIM; ++k) {
        const float dxv = dxp[k];
        const int base = (k * CC + c) * 256 + i0 * 16 + j0;
#pragma unroll
        for (int r = 0; r < 4; ++r) {
            const float4 ar = *reinterpret_cast<const float4*>(Ar + base + r * 16);
            const float4 ai = *reinterpret_cast<const float4*>(Ai + base + r * 16);
#pragma unroll
            for (int jj = 0; jj < 4; ++jj) {
                b[r][jj].x = fmaf(dxv, (&ar.x)[jj], b[r][jj].x);
                b[r][jj].y = fmaf(dxv, (&ai.x)[jj], b[r][jj].y);
            }
        }
    }

    // ---- Step 2: write B to LDS, read transposed tile, project to skew-Hermitian
#pragma unroll
    for (int r = 0; r < 4; ++r) {
        float* pa = mat + ((i0 + r) * ROWP + j0) * 2;
        reinterpret_cast<float4*>(pa)[0] =
            make_float4(b[r][0].x, b[r][0].y, b[r][1].x, b[r][1].y);
        reinterpret_cast<float4*>(pa)[1] =
            make_float4(b[r][2].x, b[r][2].y, b[r][3].x, b[r][3].y);
    }
    float2 a[4][4];  // AX tile
#pragma unroll
    for (int r = 0; r < 4; ++r)
#pragma unroll
        for (int jj = 0; jj < 4; ++jj) {
            // B[j0+jj, i0+r]
            const float2 btr =
                reinterpret_cast<const float2*>(mat + ((j0 + jj) * ROWP + (i0 + r)) * 2)[0];
            a[r][jj].x = 0.5f * (b[r][jj].x - btr.x);
            a[r][jj].y = 0.5f * (b[r][jj].y + btr.y);
        }

    // ---- Step 3: induced 1-norm: max_j sum_i |AX[i,j]|
    float cs[4];
#pragma unroll
    for (int jj = 0; jj < 4; ++jj) {
        float s_ = 0.f;
#pragma unroll
        for (int r = 0; r < 4; ++r)
            s_ += sqrtf(a[r][jj].x * a[r][jj].x + a[r][jj].y * a[r][jj].y);
        cs[jj] = s_;
    }
#pragma unroll
    for (int jj = 0; jj < 4; ++jj) {   // reduce over si (lane bits 2,3)
        cs[jj] += __shfl_xor(cs[jj], 4);
        cs[jj] += __shfl_xor(cs[jj], 8);
    }
    float mx = fmaxf(fmaxf(cs[0], cs[1]), fmaxf(cs[2], cs[3]));
    mx = fmaxf(mx, __shfl_xor(mx, 1));  // max over sj (lane bits 0,1)
    mx = fmaxf(mx, __shfl_xor(mx, 2));

    int s = 0;
    if (mx > 1.f) s = (int)ceilf(log2f(mx));
    if (s < 0) s = 0;
    if (s > 16) s = 16;
    const float scale = exp2f((float)(-s));

    // ---- Step 4: A1 = AX*scale -> LDS A;  T = I + A1/d -> LDS T
    const float invd = 1.0f / (float)TAYLOR_D;
#pragma unroll
    for (int r = 0; r < 4; ++r) {
#pragma unroll
        for (int jj = 0; jj < 4; ++jj) { a[r][jj].x *= scale; a[r][jj].y *= scale; }
        float* pa = mat + ((i0 + r) * ROWP + j0) * 2;
        reinterpret_cast<float4*>(pa)[0] =
            make_float4(a[r][0].x, a[r][0].y, a[r][1].x, a[r][1].y);
        reinterpret_cast<float4*>(pa)[1] =
            make_float4(a[r][2].x, a[r][2].y, a[r][3].x, a[r][3].y);
        float tre[4], tim[4];
#pragma unroll
        for (int jj = 0; jj < 4; ++jj) {
            tre[jj] = a[r][jj].x * invd + (((i0 + r) == (j0 + jj)) ? 1.f : 0.f);
            tim[jj] = a[r][jj].y * invd;
        }
        float* pt = tb + ((i0 + r) * ROWP + j0) * 2;
        reinterpret_cast<float4*>(pt)[0] = make_float4(tre[0], tim[0], tre[1], tim[1]);
        reinterpret_cast<float4*>(pt)[1] = make_float4(tre[2], tim[2], tre[3], tim[3]);
    }

    float2 cacc[4][4];

    // matmul: cacc = X @ Y  (16x16 complex, this lane's 4x4 tile)
    auto matmul = [&](const float* X, const float* Y) {
#pragma unroll
        for (int r = 0; r < 4; ++r)
#pragma unroll
            for (int jj = 0; jj < 4; ++jj) cacc[r][jj] = make_float2(0.f, 0.f);
#pragma unroll 4
        for (int k = 0; k < 16; ++k) {
            float2 x[4], y[4];
#pragma unroll
            for (int r = 0; r < 4; ++r)
                x[r] = reinterpret_cast<const float2*>(X + ((i0 + r) * ROWP + k) * 2)[0];
            const float4 y01 = reinterpret_cast<const float4*>(Y + (k * ROWP + j0) * 2)[0];
            const float4 y23 = reinterpret_cast<const float4*>(Y + (k * ROWP + j0) * 2)[1];
            y[0] = make_float2(y01.x, y01.y); y[1] = make_float2(y01.z, y01.w);
            y[2] = make_float2(y23.x, y23.y); y[3] = make_float2(y23.z, y23.w);
#pragma unroll
            for (int r = 0; r < 4; ++r)
#pragma unroll
                for (int jj = 0; jj < 4; ++jj) {
                    cacc[r][jj].x = fmaf(x[r].x, y[jj].x, cacc[r][jj].x);
                    cacc[r][jj].x = fmaf(-x[r].y, y[jj].y, cacc[r][jj].x);
                    cacc[r][jj].y = fmaf(x[r].x, y[jj].y, cacc[r][jj].y);
                    cacc[r][jj].y = fmaf(x[r].y, y[jj].x, cacc[r][jj].y);
                }
        }
    };

    auto store_T = [&]() {
#pragma unroll
        for (int r = 0; r < 4; ++r) {
            float* pt = tb + ((i0 + r) * ROWP + j0) * 2;
            reinterpret_cast<float4*>(pt)[0] =
                make_float4(cacc[r][0].x, cacc[r][0].y, cacc[r][1].x, cacc[r][1].y);
            reinterpret_cast<float4*>(pt)[1] =
                make_float4(cacc[r][2].x, cacc[r][2].y, cacc[r][3].x, cacc[r][3].y);
        }
    };

    // ---- Step 5: Horner: T <- I + (A*T)/mm, mm = d-1 .. 1   (9 matmuls)
#pragma unroll 1
    for (int mm = TAYLOR_D - 1; mm >= 1; --mm) {
        matmul(mat, tb);
        const float inv = 1.0f / (float)mm;
#pragma unroll
        for (int r = 0; r < 4; ++r)
#pragma unroll
            for (int jj = 0; jj < 4; ++jj) {
                cacc[r][jj].x = cacc[r][jj].x * inv + (((i0 + r) == (j0 + jj)) ? 1.f : 0.f);
                cacc[r][jj].y *= inv;
            }
        store_T();
    }

    // ---- Step 6: s squarings (divergent trip count across groups is fine)
#pragma unroll 1
    for (int step = 0; step < s; ++step) {
        matmul(tb, tb);
        store_T();
    }

    // ---- Step 7: write result
    if (real_only) {
        float* po = out + (size_t)m * 256;
#pragma unroll
        for (int r = 0; r < 4; ++r)
            *reinterpret_cast<float4*>(po + (i0 + r) * 16 + j0) =
                make_float4(cacc[r][0].x, cacc[r][1].x, cacc[r][2].x, cacc[r][3].x);
    } else {
        float* po = out + (size_t)m * 512;
#pragma unroll
        for (int r = 0; r < 4; ++r) {
            float* p = po + ((i0 + r) * 16 + j0) * 2;
            reinterpret_cast<float4*>(p)[0] =
                make_float4(cacc[r][0].x, cacc[r][0].y, cacc[r][1].x, cacc[r][1].y);
            reinterpret_cast<float4*>(p)[1] =
                make_float4(cacc[r][2].x, cacc[r][2].y, cacc[r][3].x, cacc[r][3].y);
        }
    }
}

// ---------------------------------------------------------------------------
extern "C" void kernel_launch(void* const* d_in, const int* in_sizes, int n_in,
                              void* d_out, int out_size, void* d_ws, size_t ws_size,
                              hipStream_t stream)
{
    const float* dX = (const float*)d_in[0];
    const float* Ar = (const float*)d_in[1];
    const float* Ai = (const float*)d_in[2];
    float* out = (float*)d_out;

    // out_size == NMAT*256  -> harness wants float32 real part (expected).
    // out_size == NMAT*512  -> interleaved re/im floats (fallback).
    const int real_only = (out_size < NMAT * 512) ? 1 : 0;

    hipLaunchKernelGGL(fused_expm_kernel, dim3(NMAT / MPB), dim3(128), 0, stream,
                       dX, Ar, Ai, out, real_only);
}

// Round 4
// 383.011 us; speedup vs baseline: 1.5369x; 1.5369x over previous
//
#include <hip/hip_runtime.h>
#include <math.h>

// Problem constants
#define NN       16384
#define IN_DIM   64
#define CC       4
#define NMAT     (NN * CC)           // 65536 matrices
#define ROWF     36                  // floats per LDS row (16 complex + 2 pad)
#define BUFW     (16 * ROWF)         // 576 floats per buffer
#define MWORDS   (2 * BUFW + 4)      // 1156 floats per matrix region (4-bank stagger)
#define MPB      8                   // matrices per block (128 threads, 2 waves)

// Taylor coefficients 1/k!
#define C0 1.0f
#define C1 1.0f
#define C2 0.5f
#define C3 0.16666666666666666f
#define C4 0.041666666666666664f
#define C5 0.008333333333333333f
#define C6 0.001388888888888889f
#define C7 1.984126984126984e-4f
#define C8 2.48015873015873e-5f

// ---------------------------------------------------------------------------
// Phase 1 (ws path): B[n,c,i,j] = sum_k dX[n,k] * (Ar + i*Ai)[k,c,i,j]
// 8 n's per thread -> A-row loads amortized 8x. Fully coalesced stores.
// ---------------------------------------------------------------------------
__global__ __launch_bounds__(256)
void ax_kernel(const float* __restrict__ dX, const float* __restrict__ Ar,
               const float* __restrict__ Ai, float* __restrict__ ws)
{
    const int t  = threadIdx.x;
    const int nb = blockIdx.x * 8;         // 8 n's per block
    const int c  = t >> 6;
    const int i  = (t >> 2) & 15;
    const int j0 = (t & 3) * 4;

    float accre[8][4], accim[8][4];
#pragma unroll
    for (int nn_ = 0; nn_ < 8; ++nn_)
#pragma unroll
        for (int jj = 0; jj < 4; ++jj) { accre[nn_][jj] = 0.f; accim[nn_][jj] = 0.f; }

#pragma unroll 2
    for (int k = 0; k < IN_DIM; ++k) {
        const int base = (k * CC + c) * 256 + i * 16 + j0;
        const float4 ar = *reinterpret_cast<const float4*>(Ar + base);
        const float4 ai = *reinterpret_cast<const float4*>(Ai + base);
#pragma unroll
        for (int nn_ = 0; nn_ < 8; ++nn_) {
            const float dxv = dX[(nb + nn_) * IN_DIM + k];  // block-uniform -> s_load
#pragma unroll
            for (int jj = 0; jj < 4; ++jj) {
                accre[nn_][jj] = fmaf(dxv, (&ar.x)[jj], accre[nn_][jj]);
                accim[nn_][jj] = fmaf(dxv, (&ai.x)[jj], accim[nn_][jj]);
            }
        }
    }
#pragma unroll
    for (int nn_ = 0; nn_ < 8; ++nn_) {
        const int m = (nb + nn_) * CC + c;
        float* o = ws + (size_t)m * 512 + (i * 16 + j0) * 2;
        reinterpret_cast<float4*>(o)[0] =
            make_float4(accre[nn_][0], accim[nn_][0], accre[nn_][1], accim[nn_][1]);
        reinterpret_cast<float4*>(o)[1] =
            make_float4(accre[nn_][2], accim[nn_][2], accre[nn_][3], accim[nn_][3]);
    }
}

// ---------------------------------------------------------------------------
// Phase 2: per 16x16 complex matrix: skew-projection, 1-norm -> s, scale,
// expm via Paterson-Stockmeyer degree-8 (4 matmuls), then s squarings.
// One matrix per 16-lane group, 4x4 complex tile per lane; all LDS traffic
// is per-lane-distinct or same-wave ordered (in-order DS pipe, no barriers).
// ---------------------------------------------------------------------------
__global__ __launch_bounds__(128, 2)
void expm_kernel(const float* __restrict__ dX, const float* __restrict__ Ar,
                 const float* __restrict__ Ai, const float* __restrict__ ws,
                 float* __restrict__ out, const int use_ws, const int real_only)
{
    __shared__ __align__(16) float lds[MPB * MWORDS];

    const int t   = threadIdx.x;
    const int grp = t >> 4;
    const int sub = t & 15;
    const int si  = sub >> 2, sj = sub & 3;
    const int i0  = si * 4,  j0 = sj * 4;

    float* buf0 = lds + grp * MWORDS;   // A, then T
    float* buf1 = buf0 + BUFW;          // A^2 (Z)

    const int m = blockIdx.x * MPB + grp;
    const int n = m >> 2;
    const int c = m & 3;

    // ---- obtain skew tile a[r][jj] = AX[i0+r, j0+jj] = 0.5*(B[i,j] - conj(B[j,i]))
    float2 a[4][4];
    if (use_ws) {
        const float* g = ws + (size_t)m * 512;
        float bs[4][8];   // straight rows:   bs[r][2t+e] = B[i0+r, j0+t].{re,im}
        float wf[4][8];   // transposed rows: wf[r][2t+e] = B[j0+r, i0+t].{re,im}
#pragma unroll
        for (int r = 0; r < 4; ++r) {
            *reinterpret_cast<float4*>(&bs[r][0]) =
                reinterpret_cast<const float4*>(g + ((i0 + r) * 16 + j0) * 2)[0];
            *reinterpret_cast<float4*>(&bs[r][4]) =
                reinterpret_cast<const float4*>(g + ((i0 + r) * 16 + j0) * 2)[1];
            *reinterpret_cast<float4*>(&wf[r][0]) =
                reinterpret_cast<const float4*>(g + ((j0 + r) * 16 + i0) * 2)[0];
            *reinterpret_cast<float4*>(&wf[r][4]) =
                reinterpret_cast<const float4*>(g + ((j0 + r) * 16 + i0) * 2)[1];
        }
        // register-only transpose: B[j0+jj, i0+r] = wf[jj][2r+e]  (compile-time idx)
#pragma unroll
        for (int r = 0; r < 4; ++r)
#pragma unroll
            for (int jj = 0; jj < 4; ++jj) {
                a[r][jj].x = 0.5f * (bs[r][2 * jj]     - wf[jj][2 * r]);
                a[r][jj].y = 0.5f * (bs[r][2 * jj + 1] + wf[jj][2 * r + 1]);
            }
    } else {
        // fused fallback: inline einsum for B tile + LDS transpose (per-lane-distinct)
        float2 b[4][4];
#pragma unroll
        for (int r = 0; r < 4; ++r)
#pragma unroll
            for (int jj = 0; jj < 4; ++jj) b[r][jj] = make_float2(0.f, 0.f);
        const float* dxp = dX + n * IN_DIM;
#pragma unroll 2
        for (int k = 0; k < IN_DIM; ++k) {
            const float dxv = dxp[k];
            const int base = (k * CC + c) * 256 + i0 * 16 + j0;
#pragma unroll
            for (int r = 0; r < 4; ++r) {
                const float4 ar = *reinterpret_cast<const float4*>(Ar + base + r * 16);
                const float4 ai = *reinterpret_cast<const float4*>(Ai + base + r * 16);
#pragma unroll
                for (int jj = 0; jj < 4; ++jj) {
                    b[r][jj].x = fmaf(dxv, (&ar.x)[jj], b[r][jj].x);
                    b[r][jj].y = fmaf(dxv, (&ai.x)[jj], b[r][jj].y);
                }
            }
        }
#pragma unroll
        for (int r = 0; r < 4; ++r) {
            float* pa = buf0 + (i0 + r) * ROWF + j0 * 2;
            reinterpret_cast<float4*>(pa)[0] =
                make_float4(b[r][0].x, b[r][0].y, b[r][1].x, b[r][1].y);
            reinterpret_cast<float4*>(pa)[1] =
                make_float4(b[r][2].x, b[r][2].y, b[r][3].x, b[r][3].y);
        }
#pragma unroll
        for (int r = 0; r < 4; ++r)
#pragma unroll
            for (int jj = 0; jj < 4; ++jj) {
                const float2 btr =
                    reinterpret_cast<const float2*>(buf0 + (j0 + jj) * ROWF + (i0 + r) * 2)[0];
                a[r][jj].x = 0.5f * (b[r][jj].x - btr.x);
                a[r][jj].y = 0.5f * (b[r][jj].y + btr.y);
            }
    }

    // ---- induced 1-norm: max_j sum_i |AX[i,j]|
    float cs[4];
#pragma unroll
    for (int jj = 0; jj < 4; ++jj) {
        float s_ = 0.f;
#pragma unroll
        for (int r = 0; r < 4; ++r)
            s_ += sqrtf(a[r][jj].x * a[r][jj].x + a[r][jj].y * a[r][jj].y);
        cs[jj] = s_;
    }
#pragma unroll
    for (int jj = 0; jj < 4; ++jj) {
        cs[jj] += __shfl_xor(cs[jj], 4);
        cs[jj] += __shfl_xor(cs[jj], 8);
    }
    float mx = fmaxf(fmaxf(cs[0], cs[1]), fmaxf(cs[2], cs[3]));
    mx = fmaxf(mx, __shfl_xor(mx, 1));
    mx = fmaxf(mx, __shfl_xor(mx, 2));

    int s = 0;
    if (mx > 1.f) s = (int)ceilf(log2f(mx));
    if (s < 0) s = 0;
    if (s > 16) s = 16;
    const float scale = exp2f((float)(-s));
#pragma unroll
    for (int r = 0; r < 4; ++r)
#pragma unroll
        for (int jj = 0; jj < 4; ++jj) { a[r][jj].x *= scale; a[r][jj].y *= scale; }

    float2 cacc[4][4];

    // cacc = X @ Y (16x16 complex, this lane's 4x4 tile); K-chunked b128 reads
    auto matmul = [&](const float* X, const float* Y) {
#pragma unroll
        for (int r = 0; r < 4; ++r)
#pragma unroll
            for (int jj = 0; jj < 4; ++jj) cacc[r][jj] = make_float2(0.f, 0.f);
#pragma unroll
        for (int K = 0; K < 4; ++K) {
            float4 xv[4][2], yv[4][2];
#pragma unroll
            for (int r = 0; r < 4; ++r) {
                const float* px = X + (i0 + r) * ROWF + K * 8;
                xv[r][0] = reinterpret_cast<const float4*>(px)[0];
                xv[r][1] = reinterpret_cast<const float4*>(px)[1];
            }
#pragma unroll
            for (int kk = 0; kk < 4; ++kk) {
                const float* py = Y + (K * 4 + kk) * ROWF + j0 * 2;
                yv[kk][0] = reinterpret_cast<const float4*>(py)[0];
                yv[kk][1] = reinterpret_cast<const float4*>(py)[1];
            }
#pragma unroll
            for (int kk = 0; kk < 4; ++kk) {
#pragma unroll
                for (int r = 0; r < 4; ++r) {
                    const float xr = (&xv[r][kk >> 1].x)[(kk & 1) * 2];
                    const float xi = (&xv[r][kk >> 1].x)[(kk & 1) * 2 + 1];
#pragma unroll
                    for (int jj = 0; jj < 4; ++jj) {
                        const float yr = (&yv[kk][jj >> 1].x)[(jj & 1) * 2];
                        const float yi = (&yv[kk][jj >> 1].x)[(jj & 1) * 2 + 1];
                        cacc[r][jj].x = fmaf(xr, yr, cacc[r][jj].x);
                        cacc[r][jj].x = fmaf(-xi, yi, cacc[r][jj].x);
                        cacc[r][jj].y = fmaf(xr, yi, cacc[r][jj].y);
                        cacc[r][jj].y = fmaf(xi, yr, cacc[r][jj].y);
                    }
                }
            }
        }
    };

    auto store_cacc = [&](float* B) {
#pragma unroll
        for (int r = 0; r < 4; ++r) {
            float* p = B + (i0 + r) * ROWF + j0 * 2;
            reinterpret_cast<float4*>(p)[0] =
                make_float4(cacc[r][0].x, cacc[r][0].y, cacc[r][1].x, cacc[r][1].y);
            reinterpret_cast<float4*>(p)[1] =
                make_float4(cacc[r][2].x, cacc[r][2].y, cacc[r][3].x, cacc[r][3].y);
        }
    };

    // ---- store A1 -> buf0; Z = A1^2 -> registers a2 + buf1
#pragma unroll
    for (int r = 0; r < 4; ++r) {
        float* p = buf0 + (i0 + r) * ROWF + j0 * 2;
        reinterpret_cast<float4*>(p)[0] =
            make_float4(a[r][0].x, a[r][0].y, a[r][1].x, a[r][1].y);
        reinterpret_cast<float4*>(p)[1] =
            make_float4(a[r][2].x, a[r][2].y, a[r][3].x, a[r][3].y);
    }
    matmul(buf0, buf0);
    float2 a2[4][4];
#pragma unroll
    for (int r = 0; r < 4; ++r)
#pragma unroll
        for (int jj = 0; jj < 4; ++jj) a2[r][jj] = cacc[r][jj];
    store_cacc(buf1);

    // ---- T = C8*Z + C7*A + C6*I   (leading PS block; no matmul)
#pragma unroll
    for (int r = 0; r < 4; ++r)
#pragma unroll
        for (int jj = 0; jj < 4; ++jj) {
            const float d = ((i0 + r) == (j0 + jj)) ? 1.f : 0.f;
            cacc[r][jj].x = C8 * a2[r][jj].x + C7 * a[r][jj].x + C6 * d;
            cacc[r][jj].y = C8 * a2[r][jj].y + C7 * a[r][jj].y;
        }

    // ---- 3 Horner steps: T <- T@Z + (cE*I + cO*A)
    const float cE[3] = {C4, C2, C0};
    const float cO[3] = {C5, C3, C1};
#pragma unroll 1
    for (int h = 0; h < 3; ++h) {
        store_cacc(buf0);
        matmul(buf0, buf1);
        const float e = cE[h], o = cO[h];
#pragma unroll
        for (int r = 0; r < 4; ++r)
#pragma unroll
            for (int jj = 0; jj < 4; ++jj) {
                const float d = ((i0 + r) == (j0 + jj)) ? 1.f : 0.f;
                cacc[r][jj].x += o * a[r][jj].x + e * d;
                cacc[r][jj].y += o * a[r][jj].y;
            }
    }

    // ---- s squarings (per-group divergent trip count is fine)
#pragma unroll 1
    for (int step = 0; step < s; ++step) {
        store_cacc(buf0);
        matmul(buf0, buf0);
    }

    // ---- write result
    if (real_only) {
        float* po = out + (size_t)m * 256;
#pragma unroll
        for (int r = 0; r < 4; ++r)
            *reinterpret_cast<float4*>(po + (i0 + r) * 16 + j0) =
                make_float4(cacc[r][0].x, cacc[r][1].x, cacc[r][2].x, cacc[r][3].x);
    } else {
        float* po = out + (size_t)m * 512;
#pragma unroll
        for (int r = 0; r < 4; ++r) {
            float* p = po + ((i0 + r) * 16 + j0) * 2;
            reinterpret_cast<float4*>(p)[0] =
                make_float4(cacc[r][0].x, cacc[r][0].y, cacc[r][1].x, cacc[r][1].y);
            reinterpret_cast<float4*>(p)[1] =
                make_float4(cacc[r][2].x, cacc[r][2].y, cacc[r][3].x, cacc[r][3].y);
        }
    }
}

// ---------------------------------------------------------------------------
extern "C" void kernel_launch(void* const* d_in, const int* in_sizes, int n_in,
                              void* d_out, int out_size, void* d_ws, size_t ws_size,
                              hipStream_t stream)
{
    const float* dX = (const float*)d_in[0];
    const float* Ar = (const float*)d_in[1];
    const float* Ai = (const float*)d_in[2];
    float* out = (float*)d_out;
    float* ws  = (float*)d_ws;

    const int real_only = (out_size < NMAT * 512) ? 1 : 0;
    const size_t need = (size_t)NMAT * 512 * sizeof(float);
    const int use_ws = (ws_size >= need) ? 1 : 0;

    if (use_ws)
        hipLaunchKernelGGL(ax_kernel, dim3(NN / 8), dim3(256), 0, stream, dX, Ar, Ai, ws);
    hipLaunchKernelGGL(expm_kernel, dim3(NMAT / MPB), dim3(128), 0, stream,
                       dX, Ar, Ai, ws, out, use_ws, real_only);
}